// Round 15
// baseline (494.912 us; speedup 1.0000x reference)
//
#include <hip/hip_runtime.h>
#include <stdint.h>

typedef unsigned short u16;
typedef unsigned int   u32;
typedef short s16x8 __attribute__((ext_vector_type(8)));
typedef float f32x4 __attribute__((ext_vector_type(4)));

#define NB    16384   // batch
#define NIN   1024
#define WLY   512
#define NLAY  8
#define NNODE (NIN + NLAY * WLY)   // 5120
#define BN    64      // batch columns per block

__device__ __forceinline__ u16 f2bf(float f) {
  union { float f; u32 u; } c; c.f = f;
  return (u16)((c.u + 0x7fffu + ((c.u >> 16) & 1u)) >> 16);   // RNE
}
__device__ __forceinline__ float bf2f(u16 h) {
  union { u32 u; float f; } c; c.u = ((u32)h) << 16;
  return c.f;
}

#define SCHED0() __builtin_amdgcn_sched_barrier(0)
#define BAR()    __builtin_amdgcn_s_barrier()
#define WAITLG0() asm volatile("s_waitcnt lgkmcnt(0)" ::: "memory")

// ---------- prep: fragment-major Wfrag (r3..r13-proven) ----------
__global__ void prep_w(const float* __restrict__ W, const float* __restrict__ Mk,
                       u16* __restrict__ Wm) {
  int id   = blockIdx.x * 256 + threadIdx.x;   // 262144
  int lane = id & 63;
  int chunk = id >> 6;                         // 0..4095
  int kf = chunk & 1;
  int mb = (chunk >> 1) & 31;
  int kt = (chunk >> 6) & 7;
  int l  = chunk >> 9;
  int m  = (mb << 4) + (lane & 15);
  int k0 = (kt << 6) + (kf << 5) + ((lane >> 4) << 3);
  size_t base = ((size_t)l << 18) + (size_t)m * 512 + k0;
  const float4* w4 = (const float4*)(W + base);
  const float4* k4 = (const float4*)(Mk + base);
  float4 w0 = w4[0], w1 = w4[1];
  float4 k0v = k4[0], k1v = k4[1];
  u32 p0 = (u32)f2bf(w0.x * k0v.x) | ((u32)f2bf(w0.y * k0v.y) << 16);
  u32 p1 = (u32)f2bf(w0.z * k0v.z) | ((u32)f2bf(w0.w * k0v.w) << 16);
  u32 p2 = (u32)f2bf(w1.x * k1v.x) | ((u32)f2bf(w1.y * k1v.y) << 16);
  u32 p3 = (u32)f2bf(w1.z * k1v.z) | ((u32)f2bf(w1.w * k1v.w) << 16);
  uint4 v; v.x = p0; v.y = p1; v.z = p2; v.w = p3;
  *(uint4*)(Wm + ((size_t)chunk << 9) + (lane << 3)) = v;
}

// ---------- fused 8-layer network: 2 barriers/layer macro-phase ----------
// Layer: S-phase {8 GLD up front, STW/TRANSP interleaved (Graw[2] ring,
// wave-local) into 8 conflict-free 8KB Gswz slabs} | lgkm0+BAR |
// MM-phase {8x (LDA ring-2 + 32 MFMA), barrier-free} | epilogue.
// ABL: 0=full  1=gather row-0 (locality probe)  2=no V-epilogue write
//      3=no x-prologue.  CLONE=1 -> final layer to V (scratch).
template<int ABL, int CLONE>
__global__ __launch_bounds__(512, 2) void fused_net(
    const float* __restrict__ x, const u16* __restrict__ Wfrag,
    const float* __restrict__ bias, const int* __restrict__ in_idx,
    u16* __restrict__ V, float* __restrict__ out) {

  __shared__ __align__(16) u16 Graw[2][64 * 72];  // k-major, 144B rows (18KB)
  __shared__ __align__(16) u16 Gswz[8][4096];     // 8 slabs n-major swz (64KB)
  __shared__ __align__(16) u16 Ebuf[512 * 72];    // epilogue / x-transpose

  int t = threadIdx.x;
  int lane = t & 63, w = t >> 6;
  int mlane = lane & 15, g = lane >> 4;
  int n0 = blockIdx.x * BN;
  int krow  = (w << 3) + (lane >> 3);   // staged V-row slot (own wave: 8w..8w+7)
  int kcol8 = lane & 7;                 // 8-elem batch chunk

  // ---- x prologue: V[c][n0..n0+64) = bf16(x[n][c]) for c<1024 ----
  if constexpr (ABL != 3) {
    float* xt = (float*)Ebuf;                   // [64 b][128 c] = 32KB
    for (int cc = 0; cc < 8; ++cc) {
      #pragma unroll
      for (int it = 0; it < 4; ++it) {
        int cl = t + it * 512;
        int b = cl >> 5, p = cl & 31;
        *(float4*)(xt + b * 128 + (p << 2)) =
            *(const float4*)(x + (size_t)(n0 + b) * 1024 + cc * 128 + (p << 2));
      }
      __syncthreads();
      {
        int c = t >> 2, seg = t & 3;
        u32 p[8];
        #pragma unroll
        for (int i = 0; i < 8; ++i) {
          u16 lo = f2bf(xt[(seg * 16 + 2 * i) * 128 + c]);
          u16 hi = f2bf(xt[(seg * 16 + 2 * i + 1) * 128 + c]);
          p[i] = (u32)lo | ((u32)hi << 16);
        }
        u16* dst = V + (size_t)(cc * 128 + c) * NB + n0 + seg * 16;
        uint4 v0; v0.x = p[0]; v0.y = p[1]; v0.z = p[2]; v0.w = p[3];
        uint4 v1; v1.x = p[4]; v1.y = p[5]; v1.z = p[6]; v1.w = p[7];
        *(uint4*)dst = v0;
        *(uint4*)(dst + 8) = v1;
      }
      __syncthreads();
    }
  }

#define GLD(KT) do {                                                           \
    gv[KT] = *(const uint4*)(V + (size_t)rowv[KT] * NB + n0 + (kcol8 << 3));   \
  } while (0)

#define STW(KT) do {                                                           \
    *(uint4*)((char*)Graw[(KT) & 1] + krow * 144 + (kcol8 << 4)) = gv[KT];     \
  } while (0)

#define TRANSP(KT) do {                                                        \
    const u16* gb_ = Graw[(KT) & 1];                                           \
    u32 p0_ = (u32)gb_[(w * 8 + 0) * 72 + lane] |                              \
              ((u32)gb_[(w * 8 + 1) * 72 + lane] << 16);                       \
    u32 p1_ = (u32)gb_[(w * 8 + 2) * 72 + lane] |                              \
              ((u32)gb_[(w * 8 + 3) * 72 + lane] << 16);                       \
    u32 p2_ = (u32)gb_[(w * 8 + 4) * 72 + lane] |                              \
              ((u32)gb_[(w * 8 + 5) * 72 + lane] << 16);                       \
    u32 p3_ = (u32)gb_[(w * 8 + 6) * 72 + lane] |                              \
              ((u32)gb_[(w * 8 + 7) * 72 + lane] << 16);                       \
    uint4 vv_; vv_.x = p0_; vv_.y = p1_; vv_.z = p2_; vv_.w = p3_;             \
    *(uint4*)((char*)Gswz[KT] + lane * 128 +                                   \
              ((w * 16) ^ ((lane & 7) << 4))) = vv_;                           \
  } while (0)

#define LDA(KTN) do {                                                          \
    _Pragma("unroll") for (int mb = 0; mb < 4; ++mb)                           \
    _Pragma("unroll") for (int kf = 0; kf < 2; ++kf)                           \
      a[(KTN) & 1][mb][kf] = *(const s16x8*)(Wl +                              \
          ((size_t)((((KTN) * 32 + (w << 2) + mb) << 1) + kf) << 9) +          \
          (lane << 3));                                                        \
  } while (0)

#define MM(KT) do {                                                            \
    const char* gs_ = (const char*)Gswz[KT];                                   \
    _Pragma("unroll") for (int kf = 0; kf < 2; ++kf) {                         \
      s16x8 bfr[4];                                                            \
      _Pragma("unroll") for (int nf = 0; nf < 4; ++nf) {                       \
        int n_ = (nf << 4) + mlane;                                            \
        bfr[nf] = *(const s16x8*)(gs_ + n_ * 128 +                             \
                  (((kf << 6) + (g << 4)) ^ ((n_ & 7) << 4)));                 \
      }                                                                        \
      _Pragma("unroll") for (int mb = 0; mb < 4; ++mb)                         \
      _Pragma("unroll") for (int nf = 0; nf < 4; ++nf)                         \
        acc[mb][nf] = __builtin_amdgcn_mfma_f32_16x16x32_bf16(                 \
            a[(KT) & 1][mb][kf], bfr[nf], acc[mb][nf], 0, 0, 0);               \
    }                                                                          \
  } while (0)

  int rowv[8];
  #pragma unroll
  for (int kt = 0; kt < 8; ++kt)
    rowv[kt] = in_idx[(kt << 6) + krow];

  // ---- layer loop ----
  for (int l = 0; l < NLAY; ++l) {
    __syncthreads();   // drains prior epilogue V stores before gathers

    if constexpr (ABL == 1) {
      #pragma unroll
      for (int kt = 0; kt < 8; ++kt)
        asm volatile("v_and_b32 %0, 0, %0" : "+v"(rowv[kt]));  // row 0, load kept
    }

    const u16* Wl = Wfrag + ((size_t)l << 18);
    int node_out = NIN + l * WLY;

    f32x4 acc[4][4];
    #pragma unroll
    for (int i = 0; i < 4; ++i)
      #pragma unroll
      for (int j = 0; j < 4; ++j)
        acc[i][j] = (f32x4){0.f, 0.f, 0.f, 0.f};

    s16x8 a[2][4][2];
    uint4 gv[8];

    // ---- S-phase: all gathers in flight, wave-local stage+transpose ----
    LDA(0);
    GLD(0); GLD(1); GLD(2); GLD(3); GLD(4); GLD(5); GLD(6); GLD(7);
    STW(0); STW(1);
    TRANSP(0); STW(2);
    TRANSP(1); STW(3);
    TRANSP(2); STW(4);
    TRANSP(3); STW(5);
    TRANSP(4); STW(6);
    TRANSP(5); STW(7);
    TRANSP(6); TRANSP(7);
    SCHED0(); WAITLG0(); BAR(); SCHED0();   // ONE publish barrier; VMEM flies

    // prefetch next layer's indices during MM
    int rowvn[8];
    if (l + 1 < NLAY) {
      #pragma unroll
      for (int kt = 0; kt < 8; ++kt)
        rowvn[kt] = in_idx[((l + 1) << 9) + (kt << 6) + krow];
    } else {
      #pragma unroll
      for (int kt = 0; kt < 8; ++kt) rowvn[kt] = 0;
    }

    // ---- MM-phase: barrier-free ----
    LDA(1); MM(0);
    LDA(2); MM(1);
    LDA(3); MM(2);
    LDA(4); MM(3);
    LDA(5); MM(4);
    LDA(6); MM(5);
    LDA(7); MM(6);
    MM(7);

    #pragma unroll
    for (int kt = 0; kt < 8; ++kt) rowv[kt] = rowvn[kt];

    if (l < NLAY - 1 || CLONE) {
      // wave-private epilogue: bias+relu -> Ebuf[m][72] -> coalesced V write
      #pragma unroll
      for (int mb = 0; mb < 4; ++mb) {
        float4 bv = *(const float4*)(bias + (l << 9) + (w << 6) + (mb << 4) + (g << 2));
        float bvr[4] = {bv.x, bv.y, bv.z, bv.w};
        #pragma unroll
        for (int nf = 0; nf < 4; ++nf)
          #pragma unroll
          for (int r = 0; r < 4; ++r) {
            int m = (w << 6) + (mb << 4) + (g << 2) + r;
            int n = (nf << 4) + mlane;
            Ebuf[m * 72 + n] = f2bf(fmaxf(acc[mb][nf][r] + bvr[r], 0.f));
          }
      }
      #pragma unroll
      for (int it = 0; it < 8; ++it) {
        int row = (w << 6) + (it << 3) + (lane >> 3);
        uint4 vv = *(uint4*)(Ebuf + row * 72 + ((lane & 7) << 3));
        if constexpr (ABL == 2) {
          asm volatile("" :: "v"(vv.x), "v"(vv.y), "v"(vv.z), "v"(vv.w));
        } else {
          *(uint4*)(V + (size_t)(node_out + row) * NB + n0 + ((lane & 7) << 3)) = vv;
        }
      }
    } else {
      // final layer: stride-66 Ebuf (bank-clean column reads) -> f32 out
      #pragma unroll
      for (int mb = 0; mb < 4; ++mb) {
        float4 bv = *(const float4*)(bias + (l << 9) + (w << 6) + (mb << 4) + (g << 2));
        float bvr[4] = {bv.x, bv.y, bv.z, bv.w};
        #pragma unroll
        for (int nf = 0; nf < 4; ++nf)
          #pragma unroll
          for (int r = 0; r < 4; ++r) {
            int m = (w << 6) + (mb << 4) + (g << 2) + r;
            int n = (nf << 4) + mlane;
            Ebuf[m * 66 + n] = f2bf(fmaxf(acc[mb][nf][r] + bvr[r], 0.f));
          }
      }
      __syncthreads();
      #pragma unroll
      for (int pn = 0; pn < 8; ++pn)
        #pragma unroll
        for (int h = 0; h < 2; ++h) {
          int n = (t >> 6) + (pn << 3);
          int mbase = ((t & 63) << 2) + (h << 8);
          float4 v;
          v.x = bf2f(Ebuf[(mbase + 0) * 66 + n]);
          v.y = bf2f(Ebuf[(mbase + 1) * 66 + n]);
          v.z = bf2f(Ebuf[(mbase + 2) * 66 + n]);
          v.w = bf2f(Ebuf[(mbase + 3) * 66 + n]);
          *(float4*)(out + (size_t)(n0 + n) * 512 + mbase) = v;
        }
    }
  }
#undef GLD
#undef STW
#undef TRANSP
#undef LDA
#undef MM
}

extern "C" void kernel_launch(void* const* d_in, const int* in_sizes, int n_in,
                              void* d_out, int out_size, void* d_ws, size_t ws_size,
                              hipStream_t stream) {
  (void)in_sizes; (void)n_in; (void)out_size; (void)ws_size;
  const float* x    = (const float*)d_in[0];
  const float* W    = (const float*)d_in[1];
  const float* Mk   = (const float*)d_in[2];
  const float* bias = (const float*)d_in[3];
  const int*  inidx = (const int*)d_in[4];
  float* out = (float*)d_out;

  char* ws = (char*)d_ws;
  u16* V     = (u16*)ws;                                   // 160 MiB
  u16* Wfrag = (u16*)(ws + (size_t)NNODE * NB * 2);        // 4 MiB @ 160 MiB

  prep_w<<<dim3(1024), 256, 0, stream>>>(W, Mk, Wfrag);
  // validated run (new 2-barrier macro-phase control)
  fused_net<0, 0><<<dim3(256), 512, 0, stream>>>(x, Wfrag, bias, inidx, V, out);
  // spine ablation clones (scratch V only; out untouched)
  fused_net<0, 1><<<dim3(256), 512, 0, stream>>>(x, Wfrag, bias, inidx, V, out);
  fused_net<1, 1><<<dim3(256), 512, 0, stream>>>(x, Wfrag, bias, inidx, V, out);
  fused_net<2, 1><<<dim3(256), 512, 0, stream>>>(x, Wfrag, bias, inidx, V, out);
  fused_net<3, 1><<<dim3(256), 512, 0, stream>>>(x, Wfrag, bias, inidx, V, out);
}

// Round 16
// 109.716 us; speedup vs baseline: 4.5108x; 4.5108x over previous
//
#include <hip/hip_runtime.h>
#include <stdint.h>

typedef unsigned short u16;
typedef unsigned int   u32;
typedef short s16x8 __attribute__((ext_vector_type(8)));
typedef float f32x4 __attribute__((ext_vector_type(4)));

#define NB    16384   // batch
#define NIN   1024
#define WLY   512
#define NLAY  8
#define NNODE (NIN + NLAY * WLY)   // 5120
#define BN    64      // batch columns per block

__device__ __forceinline__ u16 f2bf(float f) {
  union { float f; u32 u; } c; c.f = f;
  return (u16)((c.u + 0x7fffu + ((c.u >> 16) & 1u)) >> 16);   // RNE
}
__device__ __forceinline__ float bf2f(u16 h) {
  union { u32 u; float f; } c; c.u = ((u32)h) << 16;
  return c.f;
}

#define SCHED0() __builtin_amdgcn_sched_barrier(0)
#define BAR()    __builtin_amdgcn_s_barrier()
#define WAITLG0() asm volatile("s_waitcnt lgkmcnt(0)" ::: "memory")

// ---------- prep: fragment-major Wfrag (r3..r13-proven) ----------
// chunk = ((l*8 + kt)*32 + mb')*2 + kf ; lane maps: m = mb'*16 + (lane&15),
// k = kt*64 + kf*32 + (lane>>4)*8 + j
__global__ void prep_w(const float* __restrict__ W, const float* __restrict__ Mk,
                       u16* __restrict__ Wm) {
  int id   = blockIdx.x * 256 + threadIdx.x;   // 262144
  int lane = id & 63;
  int chunk = id >> 6;                         // 0..4095
  int kf = chunk & 1;
  int mb = (chunk >> 1) & 31;
  int kt = (chunk >> 6) & 7;
  int l  = chunk >> 9;
  int m  = (mb << 4) + (lane & 15);
  int k0 = (kt << 6) + (kf << 5) + ((lane >> 4) << 3);
  size_t base = ((size_t)l << 18) + (size_t)m * 512 + k0;
  const float4* w4 = (const float4*)(W + base);
  const float4* k4 = (const float4*)(Mk + base);
  float4 w0 = w4[0], w1 = w4[1];
  float4 k0v = k4[0], k1v = k4[1];
  u32 p0 = (u32)f2bf(w0.x * k0v.x) | ((u32)f2bf(w0.y * k0v.y) << 16);
  u32 p1 = (u32)f2bf(w0.z * k0v.z) | ((u32)f2bf(w0.w * k0v.w) << 16);
  u32 p2 = (u32)f2bf(w1.x * k1v.x) | ((u32)f2bf(w1.y * k1v.y) << 16);
  u32 p3 = (u32)f2bf(w1.z * k1v.z) | ((u32)f2bf(w1.w * k1v.w) << 16);
  uint4 v; v.x = p0; v.y = p1; v.z = p2; v.w = p3;
  *(uint4*)(Wm + ((size_t)chunk << 9) + (lane << 3)) = v;
}

// ---------- fused 8-layer network: r13 cadence @ 16 waves (4/SIMD TLP) ----------
// 1024 threads, BN=64 unchanged. Per wave: M=32 output rows, 4 staged rows
// per tile (uint2 gathers). Same Graw/Gswz layouts+swizzle as r13; same
// 4-phase K=128 schedule with lgkm0+BAR publishes. No a-ring (TLP hides W).
__global__ __launch_bounds__(1024, 4) void fused_net(
    const float* __restrict__ x, const u16* __restrict__ Wfrag,
    const float* __restrict__ bias, const int* __restrict__ in_idx,
    u16* __restrict__ V, float* __restrict__ out) {

  __shared__ __align__(16) u16 Graw[2][64 * 72];  // k-major, 144B rows (18KB)
  __shared__ __align__(16) u16 Gswz[4][4096];     // n-major XOR-swz ring (32KB)
  __shared__ __align__(16) u16 Ebuf[512 * 72];    // epilogue / x-transpose (72KB)

  int t = threadIdx.x;
  int lane = t & 63, w = t >> 6;        // w in [0,16)
  int mlane = lane & 15, g = lane >> 4;
  int n0 = blockIdx.x * BN;
  int krow  = (w << 2) + (lane >> 4);   // staged V-row (own wave: 4w..4w+3)
  int kcol4 = lane & 15;                // 4-col (8B) chunk within row

  // ---- x prologue: V[c][n0..n0+64) = bf16(x[n][c]) for c<1024 ----
  float* xt = (float*)Ebuf;                     // [64 b][128 c] = 32KB
  for (int cc = 0; cc < 8; ++cc) {
    #pragma unroll
    for (int it = 0; it < 2; ++it) {
      int cl = t + it * 1024;                   // 0..2047
      int b = cl >> 5, p = cl & 31;
      *(float4*)(xt + b * 128 + (p << 2)) =
          *(const float4*)(x + (size_t)(n0 + b) * 1024 + cc * 128 + (p << 2));
    }
    __syncthreads();
    {
      int c = t >> 3, seg = t & 7;              // c 0..127, seg packs 8 batches
      u32 p[4];
      #pragma unroll
      for (int i = 0; i < 4; ++i) {
        u16 lo = f2bf(xt[(seg * 8 + 2 * i) * 128 + c]);
        u16 hi = f2bf(xt[(seg * 8 + 2 * i + 1) * 128 + c]);
        p[i] = (u32)lo | ((u32)hi << 16);
      }
      uint4 vv; vv.x = p[0]; vv.y = p[1]; vv.z = p[2]; vv.w = p[3];
      *(uint4*)(V + (size_t)(cc * 128 + c) * NB + n0 + (seg << 3)) = vv;
    }
    __syncthreads();
  }

#define GLD(KT) do {                                                           \
    gv[(KT) & 3] =                                                             \
        *(const uint2*)(V + (size_t)rowv[KT] * NB + n0 + (kcol4 << 2));        \
  } while (0)

#define STW(KT) do {                                                           \
    *(uint2*)((char*)Graw[(KT) & 1] + krow * 144 + (kcol4 << 3)) =             \
        gv[(KT) & 3];                                                          \
  } while (0)

#define TRANSP(KT) do {                                                        \
    const u16* gb_ = Graw[(KT) & 1];                                           \
    u32 p0_ = (u32)gb_[(w * 4 + 0) * 72 + lane] |                              \
              ((u32)gb_[(w * 4 + 1) * 72 + lane] << 16);                       \
    u32 p1_ = (u32)gb_[(w * 4 + 2) * 72 + lane] |                              \
              ((u32)gb_[(w * 4 + 3) * 72 + lane] << 16);                       \
    uint2 vv_; vv_.x = p0_; vv_.y = p1_;                                       \
    *(uint2*)((char*)Gswz[(KT) & 3] + lane * 128 +                             \
              ((w * 8) ^ ((lane & 7) << 4))) = vv_;                            \
  } while (0)

#define LDA(KTN) do {                                                          \
    _Pragma("unroll") for (int mb = 0; mb < 2; ++mb)                           \
    _Pragma("unroll") for (int kf = 0; kf < 2; ++kf)                           \
      a[mb][kf] = *(const s16x8*)(Wl +                                         \
          ((size_t)((((KTN) * 32 + (w << 1) + mb) << 1) + kf) << 9) +          \
          (lane << 3));                                                        \
  } while (0)

#define MM(KT) do {                                                            \
    const char* gs_ = (const char*)Gswz[(KT) & 3];                             \
    _Pragma("unroll") for (int kf = 0; kf < 2; ++kf) {                         \
      s16x8 bfr[4];                                                            \
      _Pragma("unroll") for (int nf = 0; nf < 4; ++nf) {                       \
        int n_ = (nf << 4) + mlane;                                            \
        bfr[nf] = *(const s16x8*)(gs_ + n_ * 128 +                             \
                  (((kf << 6) + (g << 4)) ^ ((n_ & 7) << 4)));                 \
      }                                                                        \
      _Pragma("unroll") for (int mb = 0; mb < 2; ++mb)                         \
      _Pragma("unroll") for (int nf = 0; nf < 4; ++nf)                         \
        acc[mb][nf] = __builtin_amdgcn_mfma_f32_16x16x32_bf16(                 \
            a[mb][kf], bfr[nf], acc[mb][nf], 0, 0, 0);                         \
    }                                                                          \
  } while (0)

  // ---- layer loop ----
  for (int l = 0; l < NLAY; ++l) {
    __syncthreads();   // drains prior epilogue V stores before gathers

    int rowv[8];
    #pragma unroll
    for (int kt = 0; kt < 8; ++kt)
      rowv[kt] = in_idx[(l << 9) + (kt << 6) + krow];

    const u16* Wl = Wfrag + ((size_t)l << 18);
    int node_out = NIN + l * WLY;

    f32x4 acc[2][4];
    #pragma unroll
    for (int i = 0; i < 2; ++i)
      #pragma unroll
      for (int j = 0; j < 4; ++j)
        acc[i][j] = (f32x4){0.f, 0.f, 0.f, 0.f};

    s16x8 a[2][2];
    uint2 gv[4];

    // layer prologue: tiles 0,1 staged+transposed; 2,3 in flight; A0 loaded
    GLD(0); GLD(1); GLD(2); GLD(3);
    LDA(0);
    STW(0); STW(1);
    TRANSP(0); TRANSP(1);
    SCHED0(); WAITLG0(); BAR(); SCHED0();   // publish Gswz[0,1]; VMEM flies

    // prefetch next layer's indices during MM-heavy region
    int rowvn[8];
    if (l + 1 < NLAY) {
      #pragma unroll
      for (int kt = 0; kt < 8; ++kt)
        rowvn[kt] = in_idx[((l + 1) << 9) + (kt << 6) + krow];
    } else {
      #pragma unroll
      for (int kt = 0; kt < 8; ++kt) rowvn[kt] = 0;
    }

    // phase 0: MM 0,1 | stage 2,3 | gathers 4,5 in flight
    GLD(4); GLD(5);
    MM(0); LDA(1);
    MM(1); LDA(2);
    STW(2); STW(3);
    TRANSP(2); TRANSP(3);
    SCHED0(); WAITLG0(); BAR(); SCHED0();

    // phase 1: MM 2,3 | stage 4,5 | gathers 6,7 in flight
    GLD(6); GLD(7);
    MM(2); LDA(3);
    MM(3); LDA(4);
    STW(4); STW(5);
    TRANSP(4); TRANSP(5);
    SCHED0(); WAITLG0(); BAR(); SCHED0();

    // phase 2: MM 4,5 | stage 6,7
    MM(4); LDA(5);
    MM(5); LDA(6);
    STW(6); STW(7);
    TRANSP(6); TRANSP(7);
    SCHED0(); WAITLG0(); BAR(); SCHED0();

    // phase 3: MM 6,7 (no staging)
    MM(6); LDA(7);
    MM(7);

    #pragma unroll
    for (int kt = 0; kt < 8; ++kt) rowv[kt] = rowvn[kt];

    if (l < NLAY - 1) {
      // wave-private epilogue: bias+relu -> Ebuf[m][72] -> coalesced V write
      #pragma unroll
      for (int mb = 0; mb < 2; ++mb) {
        float4 bv = *(const float4*)(bias + (l << 9) + (w << 5) + (mb << 4) + (g << 2));
        float bvr[4] = {bv.x, bv.y, bv.z, bv.w};
        #pragma unroll
        for (int nf = 0; nf < 4; ++nf)
          #pragma unroll
          for (int r = 0; r < 4; ++r) {
            int m = (w << 5) + (mb << 4) + (g << 2) + r;
            int n = (nf << 4) + mlane;
            Ebuf[m * 72 + n] = f2bf(fmaxf(acc[mb][nf][r] + bvr[r], 0.f));
          }
      }
      #pragma unroll
      for (int it = 0; it < 4; ++it) {
        int row = (w << 5) + (it << 3) + (lane >> 3);
        uint4 vv = *(uint4*)(Ebuf + row * 72 + ((lane & 7) << 3));
        *(uint4*)(V + (size_t)(node_out + row) * NB + n0 + ((lane & 7) << 3)) = vv;
      }
      // no barrier: Ebuf slab + V rows are wave-private; next layer's
      // top __syncthreads drains stores before gathers read them.
    } else {
      // final layer: stride-66 Ebuf (bank-clean column reads) -> f32 out
      #pragma unroll
      for (int mb = 0; mb < 2; ++mb) {
        float4 bv = *(const float4*)(bias + (l << 9) + (w << 5) + (mb << 4) + (g << 2));
        float bvr[4] = {bv.x, bv.y, bv.z, bv.w};
        #pragma unroll
        for (int nf = 0; nf < 4; ++nf)
          #pragma unroll
          for (int r = 0; r < 4; ++r) {
            int m = (w << 5) + (mb << 4) + (g << 2) + r;
            int n = (nf << 4) + mlane;
            Ebuf[m * 66 + n] = f2bf(fmaxf(acc[mb][nf][r] + bvr[r], 0.f));
          }
      }
      __syncthreads();
      #pragma unroll
      for (int pn = 0; pn < 4; ++pn)
        #pragma unroll
        for (int h = 0; h < 2; ++h) {
          int n = (t >> 6) + (pn << 4);
          int mbase = ((t & 63) << 2) + (h << 8);
          float4 v;
          v.x = bf2f(Ebuf[(mbase + 0) * 66 + n]);
          v.y = bf2f(Ebuf[(mbase + 1) * 66 + n]);
          v.z = bf2f(Ebuf[(mbase + 2) * 66 + n]);
          v.w = bf2f(Ebuf[(mbase + 3) * 66 + n]);
          *(float4*)(out + (size_t)(n0 + n) * 512 + mbase) = v;
        }
    }
  }
#undef GLD
#undef STW
#undef TRANSP
#undef LDA
#undef MM
}

extern "C" void kernel_launch(void* const* d_in, const int* in_sizes, int n_in,
                              void* d_out, int out_size, void* d_ws, size_t ws_size,
                              hipStream_t stream) {
  (void)in_sizes; (void)n_in; (void)out_size; (void)ws_size;
  const float* x    = (const float*)d_in[0];
  const float* W    = (const float*)d_in[1];
  const float* Mk   = (const float*)d_in[2];
  const float* bias = (const float*)d_in[3];
  const int*  inidx = (const int*)d_in[4];
  float* out = (float*)d_out;

  char* ws = (char*)d_ws;
  u16* V     = (u16*)ws;                                   // 160 MiB
  u16* Wfrag = (u16*)(ws + (size_t)NNODE * NB * 2);        // 4 MiB @ 160 MiB

  prep_w<<<dim3(1024), 256, 0, stream>>>(W, Mk, Wfrag);
  fused_net<<<dim3(256), 1024, 0, stream>>>(x, Wfrag, bias, inidx, V, out);
}